// Round 1
// baseline (348.407 us; speedup 1.0000x reference)
//
#include <hip/hip_runtime.h>
#include <hip/hip_bf16.h>
#include <stdint.h>

// Problem constants (from reference)
#define DIM   512
#define NH    8
#define HD    64
#define NB    16
#define NTOK  1024
#define KHOPS 5

typedef __attribute__((ext_vector_type(8))) short bf16x8;   // 8 bf16 = 4 VGPR (guide §3)
typedef __attribute__((ext_vector_type(4))) float f32x4;

#define LOG2E 1.4426950408889634f

__device__ __forceinline__ unsigned short f32_to_bf16(float f) {
    unsigned int u = __builtin_bit_cast(unsigned int, f);
    unsigned int r = (u + 0x7FFFu + ((u >> 16) & 1u)) >> 16;   // RNE
    return (unsigned short)r;
}

__device__ __forceinline__ float fast_exp2(float x) {
    return __builtin_amdgcn_exp2f(x);
}

#define AS1C(p) ((const __attribute__((address_space(1))) void*)(p))
#define AS3(p)  ((__attribute__((address_space(3))) void*)(p))

// ---------------------------------------------------------------------------
// fp32 -> bf16 convert (vectorized)
// ---------------------------------------------------------------------------
__global__ __launch_bounds__(256) void cvt_f32_bf16(const float* __restrict__ in,
                                                    unsigned short* __restrict__ out, int n4) {
    int i = blockIdx.x * 256 + threadIdx.x;
    if (i < n4) {
        float4 v = reinterpret_cast<const float4*>(in)[i];
        ushort4 o;
        o.x = f32_to_bf16(v.x); o.y = f32_to_bf16(v.y);
        o.z = f32_to_bf16(v.z); o.w = f32_to_bf16(v.w);
        reinterpret_cast<ushort4*>(out)[i] = o;
    }
}

// ---------------------------------------------------------------------------
// bias2[h, i, j] = rel_alpha[h] * LOG2E * sum_k softmax(hop_logits[h])[k] * Hstack[k,i,j]
// (pre-scaled by log2(e) so attention can work in base-2 exponents)
// ---------------------------------------------------------------------------
__global__ __launch_bounds__(256) void bias_kernel(const float* __restrict__ H,
                                                   const float* __restrict__ hop_logits,
                                                   const float* __restrict__ rel_alpha,
                                                   float* __restrict__ bias2) {
    __shared__ float coef[NH][KHOPS];
    int tid = threadIdx.x;
    if (tid < NH) {
        float m = -1e30f;
        for (int k = 0; k < KHOPS; ++k) m = fmaxf(m, hop_logits[tid * KHOPS + k]);
        float e[KHOPS]; float s = 0.f;
        for (int k = 0; k < KHOPS; ++k) {
            e[k] = fast_exp2((hop_logits[tid * KHOPS + k] - m) * LOG2E);
            s += e[k];
        }
        float ra = rel_alpha[tid] * LOG2E / s;
        for (int k = 0; k < KHOPS; ++k) coef[tid][k] = ra * e[k];
    }
    __syncthreads();
    int idx = blockIdx.x * 256 + tid;   // over N*N = 1M
    float h0 = H[idx];
    float h1 = H[1048576 + idx];
    float h2 = H[2 * 1048576 + idx];
    float h3 = H[3 * 1048576 + idx];
    float h4 = H[4 * 1048576 + idx];
#pragma unroll
    for (int h = 0; h < NH; ++h) {
        bias2[(size_t)h * 1048576 + idx] =
            coef[h][0] * h0 + coef[h][1] * h1 + coef[h][2] * h2 + coef[h][3] * h3 + coef[h][4] * h4;
    }
}

// ---------------------------------------------------------------------------
// GEMM  C[M,Nn] = A[M,K] * Bw[Nn,K]^T   (both bf16 row-major along K; m97-style)
// 128x128 tile, BK=32, 256 threads = 4 waves in 2x2, each wave 64x64 (4x4 MFMA tiles)
// ---------------------------------------------------------------------------
template <bool BF16_OUT>
__global__ __launch_bounds__(256) void gemm_bt(const unsigned short* __restrict__ A,
                                               const unsigned short* __restrict__ Bw,
                                               void* __restrict__ Cout,
                                               const float* __restrict__ cbias,  // only fp32 path
                                               int M, int Nn, int K) {
    __shared__ unsigned short As[128 * 32];
    __shared__ unsigned short Bs[128 * 32];
    const int tid  = threadIdx.x;
    const int lane = tid & 63;
    const int w    = tid >> 6;
    const int wr   = (w >> 1) * 64, wc = (w & 1) * 64;
    const int l15  = lane & 15, quad = lane >> 4;
    const int m0   = blockIdx.x * 128, n0 = blockIdx.y * 128;

    f32x4 acc[4][4];
#pragma unroll
    for (int i = 0; i < 4; ++i)
#pragma unroll
        for (int j = 0; j < 4; ++j) { acc[i][j][0] = 0.f; acc[i][j][1] = 0.f; acc[i][j][2] = 0.f; acc[i][j][3] = 0.f; }

    for (int k0 = 0; k0 < K; k0 += 32) {
        __syncthreads();
        // stage A,B tiles: 128 rows x 32 k, 16B chunks; chunk c: row=c>>2, khalf=c&3
#pragma unroll
        for (int t = 0; t < 2; ++t) {
            int c = t * 256 + w * 64 + lane;
            int r = c >> 2, kh = c & 3;
            const unsigned short* ga = A  + (size_t)(m0 + r) * K + k0 + kh * 8;
            const unsigned short* gb = Bw + (size_t)(n0 + r) * K + k0 + kh * 8;
            __builtin_amdgcn_global_load_lds(AS1C(ga), AS3(&As[(t * 256 + w * 64) * 8]), 16, 0, 0);
            __builtin_amdgcn_global_load_lds(AS1C(gb), AS3(&Bs[(t * 256 + w * 64) * 8]), 16, 0, 0);
        }
        __syncthreads();
        bf16x8 af[4], bfr[4];
#pragma unroll
        for (int rt = 0; rt < 4; ++rt)
            af[rt] = *reinterpret_cast<const bf16x8*>(&As[(wr + rt * 16 + l15) * 32 + quad * 8]);
#pragma unroll
        for (int ct = 0; ct < 4; ++ct)
            bfr[ct] = *reinterpret_cast<const bf16x8*>(&Bs[(wc + ct * 16 + l15) * 32 + quad * 8]);
#pragma unroll
        for (int rt = 0; rt < 4; ++rt)
#pragma unroll
            for (int ct = 0; ct < 4; ++ct)
                acc[rt][ct] = __builtin_amdgcn_mfma_f32_16x16x32_bf16(af[rt], bfr[ct], acc[rt][ct], 0, 0, 0);
    }

    // epilogue: C/D layout col=lane&15, row=quad*4+reg (verified m89/m91)
    if (BF16_OUT) {
        unsigned short* C = (unsigned short*)Cout;
#pragma unroll
        for (int rt = 0; rt < 4; ++rt)
#pragma unroll
            for (int ct = 0; ct < 4; ++ct)
#pragma unroll
                for (int reg = 0; reg < 4; ++reg) {
                    int row = m0 + wr + rt * 16 + quad * 4 + reg;
                    int col = n0 + wc + ct * 16 + l15;
                    C[(size_t)row * Nn + col] = f32_to_bf16(acc[rt][ct][reg]);
                }
    } else {
        float* C = (float*)Cout;
#pragma unroll
        for (int ct = 0; ct < 4; ++ct) {
            int col = n0 + wc + ct * 16 + l15;
            float bv = cbias[col];
#pragma unroll
            for (int rt = 0; rt < 4; ++rt)
#pragma unroll
                for (int reg = 0; reg < 4; ++reg) {
                    int row = m0 + wr + rt * 16 + quad * 4 + reg;
                    C[(size_t)row * Nn + col] = acc[rt][ct][reg] + bv;
                }
        }
    }
}

// ---------------------------------------------------------------------------
// V transpose: qkv V-columns [B,N,(v)H,64] -> vt [B,H,64,N]
// one block per (b, h, 64-row j-tile); LDS tile 64x64, stride 66 (conflict-free b32 writes)
// ---------------------------------------------------------------------------
__global__ __launch_bounds__(256) void transpose_v(const unsigned short* __restrict__ qkv,
                                                   unsigned short* __restrict__ vt) {
    __shared__ unsigned short Ts[64 * 66];
    const int tid = threadIdx.x;
    const int jt = blockIdx.x, h = blockIdx.y, b = blockIdx.z;
    const int j0 = jt * 64;
#pragma unroll
    for (int t = 0; t < 2; ++t) {
        int c = t * 256 + tid;
        int j = c >> 3, dh = c & 7;   // row j of tile, 8-elem d-chunk
        const uint32_t* g = reinterpret_cast<const uint32_t*>(
            qkv + (size_t)(b * 1024 + j0 + j) * 1536 + 1024 + h * 64 + dh * 8);
        uint32_t d0 = g[0], d1 = g[1], d2 = g[2], d3 = g[3];
        uint32_t* ls = reinterpret_cast<uint32_t*>(&Ts[j * 66 + dh * 8]);
        ls[0] = d0; ls[1] = d1; ls[2] = d2; ls[3] = d3;
    }
    __syncthreads();
#pragma unroll
    for (int t = 0; t < 2; ++t) {
        int c = t * 256 + tid;
        int d = c >> 3, jh = c & 7;   // output row d, 8-elem j-chunk
        unsigned short tmp[8];
#pragma unroll
        for (int e = 0; e < 8; ++e) tmp[e] = Ts[(jh * 8 + e) * 66 + d];
        uint32_t o0 = (uint32_t)tmp[0] | ((uint32_t)tmp[1] << 16);
        uint32_t o1 = (uint32_t)tmp[2] | ((uint32_t)tmp[3] << 16);
        uint32_t o2 = (uint32_t)tmp[4] | ((uint32_t)tmp[5] << 16);
        uint32_t o3 = (uint32_t)tmp[6] | ((uint32_t)tmp[7] << 16);
        uint32_t* gout = reinterpret_cast<uint32_t*>(
            vt + ((size_t)((b * 8 + h) * 64 + d)) * 1024 + j0 + jh * 8);
        gout[0] = o0; gout[1] = o1; gout[2] = o2; gout[3] = o3;
    }
}

// ---------------------------------------------------------------------------
// Flash attention: block = (qtile of 128 rows, h, b); 4 waves x 32 rows each.
// K/Q/V fragments loaded directly from global (line-perfect patterns, L2-served).
// LDS only for the P C-layout -> A-layout round trip (per-wave private).
// ---------------------------------------------------------------------------
__global__ __launch_bounds__(256) void flash_attn(const unsigned short* __restrict__ qkv,
                                                  const unsigned short* __restrict__ vt,
                                                  const float* __restrict__ bias2,
                                                  unsigned short* __restrict__ aout) {
    __shared__ unsigned short Ps[4 * 32 * 80];   // per wave: 32 rows x stride 80
    const int tid  = threadIdx.x;
    const int lane = tid & 63, w = tid >> 6;
    const int l15  = lane & 15, quad = lane >> 4;
    const int qt = blockIdx.x, h = blockIdx.y, b = blockIdx.z;
    const int i0 = qt * 128 + w * 32;            // this wave's first query row
    const float kscale = 0.125f * LOG2E;         // SCALE * log2(e)

    // Q fragments: A[m=lane&15][k=quad*8+j] (m120-verified)
    bf16x8 qf[2][2];
#pragma unroll
    for (int rt = 0; rt < 2; ++rt)
#pragma unroll
        for (int ks = 0; ks < 2; ++ks)
            qf[rt][ks] = *reinterpret_cast<const bf16x8*>(
                qkv + (size_t)(b * 1024 + i0 + rt * 16 + l15) * 1536 + h * 64 + ks * 32 + quad * 8);

    f32x4 o[2][4];
    float mrow[2][4], lrow[2][4];
#pragma unroll
    for (int rt = 0; rt < 2; ++rt) {
#pragma unroll
        for (int nt = 0; nt < 4; ++nt) { o[rt][nt][0] = 0.f; o[rt][nt][1] = 0.f; o[rt][nt][2] = 0.f; o[rt][nt][3] = 0.f; }
#pragma unroll
        for (int reg = 0; reg < 4; ++reg) { mrow[rt][reg] = -1e30f; lrow[rt][reg] = 0.f; }
    }

    const unsigned short* kbase = qkv + 512 + h * 64;
    const unsigned short* vbase = vt + (size_t)((b * 8 + h) * 64) * 1024;
    const float* bbase = bias2 + (size_t)h * 1048576;
    unsigned short* ps = &Ps[w * 32 * 80];

    for (int j0 = 0; j0 < 1024; j0 += 64) {
        // K fragments: B[k=d][n=j], lane n = jt*16+l15 -> K row, contiguous 8 d's
        bf16x8 kf[4][2];
#pragma unroll
        for (int jt = 0; jt < 4; ++jt)
#pragma unroll
            for (int ks = 0; ks < 2; ++ks)
                kf[jt][ks] = *reinterpret_cast<const bf16x8*>(
                    kbase + (size_t)(b * 1024 + j0 + jt * 16 + l15) * 1536 + ks * 32 + quad * 8);

        // S = Q K^T
        f32x4 s[2][4];
#pragma unroll
        for (int rt = 0; rt < 2; ++rt)
#pragma unroll
            for (int jt = 0; jt < 4; ++jt) {
                s[rt][jt][0] = 0.f; s[rt][jt][1] = 0.f; s[rt][jt][2] = 0.f; s[rt][jt][3] = 0.f;
#pragma unroll
                for (int ks = 0; ks < 2; ++ks)
                    s[rt][jt] = __builtin_amdgcn_mfma_f32_16x16x32_bf16(qf[rt][ks], kf[jt][ks], s[rt][jt], 0, 0, 0);
            }

        // scale + bias (already *log2e), then online softmax in base-2
        float sv[2][4][4];
#pragma unroll
        for (int rt = 0; rt < 2; ++rt)
#pragma unroll
            for (int jt = 0; jt < 4; ++jt)
#pragma unroll
                for (int reg = 0; reg < 4; ++reg) {
                    float bb = bbase[(size_t)(i0 + rt * 16 + quad * 4 + reg) * 1024 + j0 + jt * 16 + l15];
                    sv[rt][jt][reg] = s[rt][jt][reg] * kscale + bb;
                }

#pragma unroll
        for (int rt = 0; rt < 2; ++rt) {
            float rmax[4], alpha[4], rsum[4];
#pragma unroll
            for (int reg = 0; reg < 4; ++reg) {
                rmax[reg] = fmaxf(fmaxf(sv[rt][0][reg], sv[rt][1][reg]), fmaxf(sv[rt][2][reg], sv[rt][3][reg]));
            }
#pragma unroll
            for (int reg = 0; reg < 4; ++reg) {
                rmax[reg] = fmaxf(rmax[reg], __shfl_xor(rmax[reg], 1, 64));
                rmax[reg] = fmaxf(rmax[reg], __shfl_xor(rmax[reg], 2, 64));
                rmax[reg] = fmaxf(rmax[reg], __shfl_xor(rmax[reg], 4, 64));
                rmax[reg] = fmaxf(rmax[reg], __shfl_xor(rmax[reg], 8, 64));
            }
#pragma unroll
            for (int reg = 0; reg < 4; ++reg) {
                float mnew = fmaxf(mrow[rt][reg], rmax[reg]);
                alpha[reg] = fast_exp2(mrow[rt][reg] - mnew);
                mrow[rt][reg] = mnew;
                rsum[reg] = 0.f;
            }
#pragma unroll
            for (int jt = 0; jt < 4; ++jt)
#pragma unroll
                for (int reg = 0; reg < 4; ++reg) {
                    float p = fast_exp2(sv[rt][jt][reg] - mrow[rt][reg]);
                    sv[rt][jt][reg] = p;
                    rsum[reg] += p;
                }
#pragma unroll
            for (int reg = 0; reg < 4; ++reg) {
                rsum[reg] += __shfl_xor(rsum[reg], 1, 64);
                rsum[reg] += __shfl_xor(rsum[reg], 2, 64);
                rsum[reg] += __shfl_xor(rsum[reg], 4, 64);
                rsum[reg] += __shfl_xor(rsum[reg], 8, 64);
                lrow[rt][reg] = lrow[rt][reg] * alpha[reg] + rsum[reg];
            }
#pragma unroll
            for (int nt = 0; nt < 4; ++nt)
#pragma unroll
                for (int reg = 0; reg < 4; ++reg) o[rt][nt][reg] *= alpha[reg];
            // P -> LDS in bf16 (C-layout write; stride 80 => quad bank-shift 8, conflict-free)
#pragma unroll
            for (int jt = 0; jt < 4; ++jt)
#pragma unroll
                for (int reg = 0; reg < 4; ++reg)
                    ps[(rt * 16 + quad * 4 + reg) * 80 + jt * 16 + l15] = f32_to_bf16(sv[rt][jt][reg]);
        }

        // P A-fragments (same-wave DS ordering guarantees visibility)
        bf16x8 pf[2][2];
#pragma unroll
        for (int rt = 0; rt < 2; ++rt)
#pragma unroll
            for (int ks = 0; ks < 2; ++ks)
                pf[rt][ks] = *reinterpret_cast<const bf16x8*>(ps + (rt * 16 + l15) * 80 + ks * 32 + quad * 8);

        // V fragments from transposed V: B[k=j][n=d], lane n = nt*16+l15 -> vt row d, 8 contiguous j
        bf16x8 vf[4][2];
#pragma unroll
        for (int nt = 0; nt < 4; ++nt)
#pragma unroll
            for (int ks = 0; ks < 2; ++ks)
                vf[nt][ks] = *reinterpret_cast<const bf16x8*>(
                    vbase + (size_t)(nt * 16 + l15) * 1024 + j0 + ks * 32 + quad * 8);

#pragma unroll
        for (int rt = 0; rt < 2; ++rt)
#pragma unroll
            for (int nt = 0; nt < 4; ++nt)
#pragma unroll
                for (int ks = 0; ks < 2; ++ks)
                    o[rt][nt] = __builtin_amdgcn_mfma_f32_16x16x32_bf16(pf[rt][ks], vf[nt][ks], o[rt][nt], 0, 0, 0);
    }

    // finalize: divide by l, write attn-out [B, N, H*64] bf16
#pragma unroll
    for (int rt = 0; rt < 2; ++rt) {
        float inv[4];
#pragma unroll
        for (int reg = 0; reg < 4; ++reg) inv[reg] = 1.f / lrow[rt][reg];
#pragma unroll
        for (int nt = 0; nt < 4; ++nt)
#pragma unroll
            for (int reg = 0; reg < 4; ++reg) {
                int row = b * 1024 + i0 + rt * 16 + quad * 4 + reg;
                int col = h * 64 + nt * 16 + l15;
                aout[(size_t)row * 512 + col] = f32_to_bf16(o[rt][nt][reg] * inv[reg]);
            }
    }
}

// ---------------------------------------------------------------------------
extern "C" void kernel_launch(void* const* d_in, const int* in_sizes, int n_in,
                              void* d_out, int out_size, void* d_ws, size_t ws_size,
                              hipStream_t stream) {
    const float* x          = (const float*)d_in[0];
    const float* Hstack     = (const float*)d_in[1];
    const float* hop_logits = (const float*)d_in[2];
    const float* rel_alpha  = (const float*)d_in[3];
    const float* Wqkv       = (const float*)d_in[4];
    const float* Wproj      = (const float*)d_in[5];
    const float* bproj      = (const float*)d_in[6];
    float* out = (float*)d_out;

    char* ws = (char*)d_ws;
    // workspace layout (bytes); total = 136,314,880
    unsigned short* xb    = (unsigned short*)(ws);                  // x bf16        16 MB
    unsigned short* wqb   = (unsigned short*)(ws + 16777216);       // Wqkv bf16    1.5 MB
    unsigned short* wpb   = (unsigned short*)(ws + 18350080);       // Wproj bf16   0.5 MB
    unsigned short* qkvb  = (unsigned short*)(ws + 18874368);       // qkv bf16      48 MB
    unsigned short* vtb   = (unsigned short*)(ws + 69206016);       // V^T bf16      16 MB
    float*          biasb = (float*)(ws + 85983232);                // bias fp32     32 MB
    unsigned short* aoutb = (unsigned short*)(ws + 119537664);      // attn out      16 MB

    // 1. converts
    cvt_f32_bf16<<<8192, 256, 0, stream>>>(x, xb, 2097152);          // 16384*512/4
    cvt_f32_bf16<<<768, 256, 0, stream>>>(Wqkv, wqb, 196608);        // 1536*512/4
    cvt_f32_bf16<<<256, 256, 0, stream>>>(Wproj, wpb, 65536);        // 512*512/4

    // 2. hop-bias precompute
    bias_kernel<<<4096, 256, 0, stream>>>(Hstack, hop_logits, rel_alpha, biasb);

    // 3. qkv = x @ Wqkv^T   [16384,512] x [1536,512]^T -> bf16 [16384,1536]
    gemm_bt<true><<<dim3(128, 12), 256, 0, stream>>>(xb, wqb, qkvb, nullptr, 16384, 1536, 512);

    // 4. V transpose -> [B,H,64,N]
    transpose_v<<<dim3(16, 8, 16), 256, 0, stream>>>(qkvb, vtb);

    // 5. flash attention -> [B,N,512] bf16
    flash_attn<<<dim3(8, 8, 16), 256, 0, stream>>>(qkvb, vtb, biasb, aoutb);

    // 6. out = attn_out @ Wproj^T + bproj  -> fp32
    gemm_bt<false><<<dim3(128, 4), 256, 0, stream>>>(aoutb, wpb, out, bproj, 16384, 512, 512);
}